// Round 23
// baseline (152.952 us; speedup 1.0000x reference)
//
#include <hip/hip_runtime.h>
#include <hip/hip_bf16.h>
#include <cstdint>

#define NN 8192
#define F 512
#define LOG2E 1.4426950408889634f

typedef __attribute__((ext_vector_type(8))) short bf16x8;
typedef __attribute__((ext_vector_type(4))) float f32x4;
typedef unsigned int uint32;
typedef unsigned long long u64;
typedef unsigned char uchar;

__device__ __forceinline__ short f2bf(float x){
  __hip_bfloat16 h = __float2bfloat16(x);
  return *reinterpret_cast<short*>(&h);
}

// ---------- wa = W @ a1 / W @ a2 ----------
__global__ __launch_bounds__(256) void k_wa(const float* __restrict__ W, const float* __restrict__ attn,
                     float* __restrict__ wa){
  const int lane = threadIdx.x&63, wid = threadIdx.x>>6;
  const int id = blockIdx.x*4 + wid;
  const int b = id>>9, c = id&511;
  const float4* Wr = (const float4*)(W + (size_t)c*F);
  const float4* av = (const float4*)(attn + b*F);
  float s = 0.f;
  #pragma unroll
  for (int h=0;h<2;++h){
    const int k = lane + h*64;
    const float4 wv = Wr[k], a = av[k];
    s += wv.x*a.x + wv.y*a.y + wv.z*a.z + wv.w*a.w;
  }
  for (int off=32;off;off>>=1) s += __shfl_down(s,off);
  if (lane==0) wa[id] = s;
}

// ---------- W^T -> bf16 via LDS tile ----------
__global__ __launch_bounds__(256) void k_tw(const float* __restrict__ W, short* __restrict__ WbT){
  __shared__ short t[64][72];
  const int k0 = blockIdx.x*64, n0 = blockIdx.y*64;
  #pragma unroll
  for (int it=0;it<16;++it){
    const int idx = it*256 + threadIdx.x;
    const int r = idx>>6, c = idx&63;
    t[r][c] = f2bf(W[(size_t)(k0+r)*F + n0 + c]);
  }
  __syncthreads();
  #pragma unroll
  for (int it=0;it<2;++it){
    const int idx = it*256 + threadIdx.x;
    const int n = idx>>3, g = idx&7;
    short v[8];
    #pragma unroll
    for (int e=0;e<8;++e) v[e] = t[g*8+e][n];
    *(uint4*)(WbT + (size_t)(n0+n)*F + k0 + g*8) = *(const uint4*)v;
  }
}

// ---------- fused: X->bf16 + rowAB + packed bf16 (u,w) ----------
__global__ __launch_bounds__(256) void k_prep(const float* __restrict__ X, const float* __restrict__ wa,
    short* __restrict__ Xb, float2* __restrict__ rowAB, uint32* __restrict__ uwb){
  const int lane = threadIdx.x&63, wid = threadIdx.x>>6;
  const int row = blockIdx.x*4 + wid;
  const float4* X4 = (const float4*)(X + (size_t)row*F);
  const float4* A4 = (const float4*)wa;
  const float4* B4 = (const float4*)(wa + F);
  uint2* Xb4 = (uint2*)(Xb + (size_t)row*F);
  float a1 = 0.f, a2 = 0.f;
  #pragma unroll
  for (int h=0;h<2;++h){
    const int c = lane + h*64;
    const float4 x = X4[c];
    const float4 a = A4[c];
    const float4 b = B4[c];
    a1 += x.x*a.x + x.y*a.y + x.z*a.z + x.w*a.w;
    a2 += x.x*b.x + x.y*b.y + x.z*b.z + x.w*b.w;
    short o[4] = {f2bf(x.x),f2bf(x.y),f2bf(x.z),f2bf(x.w)};
    Xb4[c] = *(const uint2*)o;
  }
  for (int off=32;off;off>>=1){ a1 += __shfl_down(a1,off); a2 += __shfl_down(a2,off); }
  if (lane==0){
    const float s1 = a1*LOG2E, s2 = a2*LOG2E;
    rowAB[row] = make_float2(exp2f(s1), exp2f(0.2f*s1));
    const float u = exp2f(s2), w = exp2f(0.2f*s2);
    uwb[row] = (uint32)(unsigned short)f2bf(u) | ((uint32)(unsigned short)f2bf(w)<<16);
  }
}

// ---------- GEMM1: h = Xb @ WbT^T, writes HT[feature][node] bf16 ----------
__global__ __launch_bounds__(256,2) void k_gemm1(const short* __restrict__ Xb,
    const short* __restrict__ WbT, short* __restrict__ HT){
  __shared__ char smem[33280];
  short* At = (short*)smem;
  short* Bt = (short*)(smem + 16384);
  const int tid=threadIdx.x, lane=tid&63, wid=tid>>6;
  const int m0 = blockIdx.x*128, n0 = blockIdx.y*128;
  f32x4 acc[2][8];
  #pragma unroll
  for (int a=0;a<2;++a)
    #pragma unroll
    for (int b=0;b<8;++b) acc[a][b] = (f32x4){0.f,0.f,0.f,0.f};

  for (int t=0;t<8;++t){
    const int k0 = t*64;
    __syncthreads();
    #pragma unroll
    for (int rnd=0;rnd<4;++rnd){
      const int s = rnd*256 + tid;
      const int n = s>>3, kc = s&7;
      uint4 va = *(const uint4*)(Xb  + (size_t)(m0+n)*F + k0 + kc*8);
      uint4 vb = *(const uint4*)(WbT + (size_t)(n0+n)*F + k0 + kc*8);
      const int off = n*128 + ((kc^(n&7))*16);
      *(uint4*)((char*)At + off) = va;
      *(uint4*)((char*)Bt + off) = vb;
    }
    __syncthreads();
    #pragma unroll
    for (int ks=0;ks<2;++ks){
      const int kc = ks*4 + (lane>>4);
      int r0 = wid*32 + (lane&15);
      int r1 = r0 + 16;
      bf16x8 af0 = *(const bf16x8*)((char*)At + r0*128 + ((kc^(r0&7))*16));
      bf16x8 af1 = *(const bf16x8*)((char*)At + r1*128 + ((kc^(r1&7))*16));
      #pragma unroll
      for (int nf=0;nf<8;++nf){
        const int c = nf*16 + (lane&15);
        bf16x8 bf = *(const bf16x8*)((char*)Bt + c*128 + ((kc^(c&7))*16));
        acc[0][nf] = __builtin_amdgcn_mfma_f32_16x16x32_bf16(af0, bf, acc[0][nf],0,0,0);
        acc[1][nf] = __builtin_amdgcn_mfma_f32_16x16x32_bf16(af1, bf, acc[1][nf],0,0,0);
      }
    }
  }
  __syncthreads();
  short* ct = (short*)smem;                 // [128][130] bf16
  #pragma unroll
  for (int mf=0;mf<2;++mf)
    #pragma unroll
    for (int nf=0;nf<8;++nf)
      #pragma unroll
      for (int q=0;q<4;++q){
        int r = wid*32 + mf*16 + (lane>>4)*4 + q;
        int c = nf*16 + (lane&15);
        ct[r*130+c] = f2bf(acc[mf][nf][q]);
      }
  __syncthreads();
  {
    const int c = tid>>1, ih0 = (tid&1)*64;
    #pragma unroll
    for (int i8=0;i8<8;++i8){
      short v[8];
      #pragma unroll
      for (int e=0;e<8;++e) v[e] = ct[(ih0+i8*8+e)*130 + c];
      *(uint4*)(HT + (size_t)(n0+c)*NN + m0 + ih0 + i8*8) = *(const uint4*)v;
    }
  }
}

// ---------- PV fused v16: R20 + phase-2 reorder (AGEN before BWRITE) ----------
// BM=64, BN=512, BK=64, 4 waves of 64x128, split-K=4. LDS 80KB -> 2 blocks/CU.
__global__ __launch_bounds__(256,2) void k_pv(const int* __restrict__ adj,
    const short* __restrict__ HT, const uint32* __restrict__ uwb,
    const float2* __restrict__ rowAB, float* __restrict__ Zp,
    float* __restrict__ P0, float* __restrict__ P1,
    float* __restrict__ P2, float* __restrict__ P3, int ksteps, int KS){
  __shared__ short Bt[512*64];       // 64 KB : row=feature, 128B/row, chunk^=(f&7)
  __shared__ short At[64*64];        // 8 KB  : row=out-row, same swizzle
  __shared__ uint32 uwl[2048];       // 8 KB packed bf16 (u,w) for this k-slice
  const int tid=threadIdx.x, lane=tid&63, wid=tid>>6;
  // XCD-affine mapping (R16-verified): XCD pair {2k,2k+1} owns kz=k.
  int mx, kz;
  if (KS == 4){
    const int id = blockIdx.x;
    kz = (id&7)>>1;
    mx = ((id>>3)<<1) + (id&1);
  } else { kz = 0; mx = blockIdx.x; }
  const int m0 = mx*64;
  const int kz0 = kz*(ksteps*64);
  float* const outs[4] = {P0,P1,P2,P3};
  float* outP = outs[kz];

  // ---- stage uw slice (2048 u32) ----
  {
    const uint4* src = (const uint4*)(uwb + kz0);
    uint4 v0 = src[tid], v1 = src[256+tid];
    ((uint4*)uwl)[tid] = v0; ((uint4*)uwl)[256+tid] = v1;
  }

  // ---- B staging: reg j covers row f = h*256 + j*32 + (tid>>3), chunk c = tid&7,
  //      holding source kc = c ^ (f&7) = (tid&7)^((tid>>3)&7) (h,j-independent).
  const int kcs = (tid&7) ^ ((tid>>3)&7);
  const short* gBa = HT + (size_t)(tid>>3)*NN + kz0 + kcs*8;  // + (h*256+j*32)*NN + t*64

  // ---- AGEN geometry: row ar=tid>>2, col-group aq=tid&3 (8 k per half)
  const int ar = tid>>2, aq = tid&3;
  const float2 E = rowAB[m0 + ar];
  const float A0 = E.x, B0c = E.y;
  const int* adjp = adj + (size_t)(m0+ar)*NN + kz0 + aq*8;    // + t*64 + h*32
  const int aoff0 = ar*128 + (((aq  ) ^ (ar&7))*16);          // h=0: chunk aq
  const int aoff1 = ar*128 + (((aq+4) ^ (ar&7))*16);          // h=1: chunk aq+4

  f32x4 acc[4][8];
  #pragma unroll
  for (int i=0;i<4;++i)
    #pragma unroll
    for (int j=0;j<8;++j) acc[i][j] = (f32x4){0.f,0.f,0.f,0.f};
  float zacc = 0.f;

  uint4 b0,b1,b2,b3,b4,b5,b6,b7;   // B regs: half 0
  uint4 c0,c1,c2,c3,c4,c5,c6,c7;   // B regs: half 1
  int4  aA0,aA1, aB0,aB1;          // adjacency sets: A=half0, B=half1 of step

#define PV_BLOAD_H0(tt) { \
    const short* g = gBa + (size_t)(tt)*64; \
    b0 = *(const uint4*)(g);                   b1 = *(const uint4*)(g + (size_t)1*32*NN); \
    b2 = *(const uint4*)(g + (size_t)2*32*NN); b3 = *(const uint4*)(g + (size_t)3*32*NN); \
    b4 = *(const uint4*)(g + (size_t)4*32*NN); b5 = *(const uint4*)(g + (size_t)5*32*NN); \
    b6 = *(const uint4*)(g + (size_t)6*32*NN); b7 = *(const uint4*)(g + (size_t)7*32*NN); }

#define PV_BLOAD_H1(tt) { \
    const short* g = gBa + (size_t)256*NN + (size_t)(tt)*64; \
    c0 = *(const uint4*)(g);                   c1 = *(const uint4*)(g + (size_t)1*32*NN); \
    c2 = *(const uint4*)(g + (size_t)2*32*NN); c3 = *(const uint4*)(g + (size_t)3*32*NN); \
    c4 = *(const uint4*)(g + (size_t)4*32*NN); c5 = *(const uint4*)(g + (size_t)5*32*NN); \
    c6 = *(const uint4*)(g + (size_t)6*32*NN); c7 = *(const uint4*)(g + (size_t)7*32*NN); }

#define PV_BWRITE_H0() { \
    uint4* d = (uint4*)Bt; \
    d[      tid] = b0; d[ 256+tid] = b1; d[ 512+tid] = b2; d[ 768+tid] = b3; \
    d[1024+tid] = b4; d[1280+tid] = b5; d[1536+tid] = b6; d[1792+tid] = b7; }

#define PV_BWRITE_H1() { \
    uint4* d = (uint4*)Bt + 2048; \
    d[      tid] = c0; d[ 256+tid] = c1; d[ 512+tid] = c2; d[ 768+tid] = c3; \
    d[1024+tid] = c4; d[1280+tid] = c5; d[1536+tid] = c6; d[1792+tid] = c7; }

#define PV_ALOAD(r0v,r1v,h,tt) { \
    r0v = *(const int4*)(adjp + (size_t)(tt)*64 + (h)*32); \
    r1v = *(const int4*)(adjp + (size_t)(tt)*64 + (h)*32 + 4); }

#define PV_AGEN(aoffv, r0v, r1v, h, tt) { \
    const uint32* uwt = &uwl[(tt)*64 + (h)*32 + aq*8]; \
    const uint4 u0 = *(const uint4*)uwt; \
    const uint4 u1 = *(const uint4*)(uwt+4); \
    const uint32 pk[8] = {u0.x,u0.y,u0.z,u0.w,u1.x,u1.y,u1.z,u1.w}; \
    const int    aa[8] = {r0v.x,r0v.y,r0v.z,r0v.w,r1v.x,r1v.y,r1v.z,r1v.w}; \
    short av[8]; \
    _Pragma("unroll") \
    for (int e=0;e<8;++e){ \
      const float u = __uint_as_float(pk[e]<<16); \
      const float w = __uint_as_float(pk[e]&0xffff0000u); \
      float v = fmaxf(A0*u, B0c*w); \
      v = (aa[e] > 0) ? v : 0.f; \
      zacc += v; \
      av[e] = f2bf(v); } \
    *(uint4*)((char*)At + (aoffv)) = *(const uint4*)av; }

#define PV_MFMA64() { \
    _Pragma("unroll") \
    for (int ks=0;ks<2;++ks){ \
      const int kc = ks*4 + (lane>>4); \
      bf16x8 af[4]; \
      _Pragma("unroll") \
      for (int mf=0;mf<4;++mf){ \
        const int r = mf*16 + (lane&15); \
        af[mf] = *(const bf16x8*)((char*)At + r*128 + ((kc^(r&7))*16)); } \
      _Pragma("unroll") \
      for (int nf=0;nf<8;++nf){ \
        const int c = wid*128 + nf*16 + (lane&15); \
        const bf16x8 bv = *(const bf16x8*)((char*)Bt + c*128 + ((kc^(c&7))*16)); \
        _Pragma("unroll") \
        for (int mf=0;mf<4;++mf) \
          acc[mf][nf] = __builtin_amdgcn_mfma_f32_16x16x32_bf16(af[mf], bv, acc[mf][nf],0,0,0); } } }

  // ---- prologue: step 0 fully staged (both halves loaded up-front) ----
  PV_ALOAD(aA0,aA1, 0, 0);
  PV_ALOAD(aB0,aB1, 1, 0);
  PV_BLOAD_H0(0);
  PV_BLOAD_H1(0);
  __syncthreads();                 // uwl visible
  PV_AGEN(aoff0, aA0,aA1, 0, 0);
  PV_AGEN(aoff1, aB0,aB1, 1, 0);
  PV_BWRITE_H0();
  PV_BWRITE_H1();
  __syncthreads();                 // tiles(0) visible

  // ---- main loop: one 64-K step per iteration, 2 barriers/step ----
  for (int t=0; t<ksteps; ++t){
    // issue ALL next-step loads before compute (full MFMA phase to land)
    if (t+1 < ksteps){
      PV_BLOAD_H0(t+1);
      PV_BLOAD_H1(t+1);
      PV_ALOAD(aA0,aA1, 0, t+1);
      PV_ALOAD(aB0,aB1, 1, t+1);
    }
    PV_MFMA64();
    __syncthreads();               // reads of Bt/At done
    if (t+1 < ksteps){
      // AGEN first: its inputs (uwl + adj regs) are ready -> VALU work covers any
      // residual latency on the in-flight B regs before BWRITE's vmcnt wait.
      PV_AGEN(aoff0, aA0,aA1, 0, t+1);
      PV_AGEN(aoff1, aB0,aB1, 1, t+1);
      PV_BWRITE_H0();
      PV_BWRITE_H1();
      __syncthreads();             // tiles(t+1) visible
    }
  }

  // per-slice Z: 4 threads per row
  zacc += __shfl_xor(zacc, 1);
  zacc += __shfl_xor(zacc, 2);
  if (aq == 0) Zp[(size_t)kz*NN + m0 + ar] = zacc;
  // raw f32 partial store
  #pragma unroll
  for (int mf=0;mf<4;++mf)
    #pragma unroll
    for (int nf=0;nf<8;++nf){
      const int col = wid*128 + nf*16 + (lane&15);
      #pragma unroll
      for (int qq=0;qq<4;++qq){
        const int row = m0 + mf*16 + (lane>>4)*4 + qq;
        outP[(size_t)row*F + col] = acc[mf][nf][qq];
      }
    }
#undef PV_BLOAD_H0
#undef PV_BLOAD_H1
#undef PV_BWRITE_H0
#undef PV_BWRITE_H1
#undef PV_ALOAD
#undef PV_AGEN
#undef PV_MFMA64
}

// ---------- reduce: out = elu( (P0+P1+P2+P3) / Z ) ----------
__global__ __launch_bounds__(256) void k_red(const float* __restrict__ P1,
    const float* __restrict__ P2, const float* __restrict__ P3,
    const float* __restrict__ Zp, float* __restrict__ out, int ks){
  const size_t i = ((size_t)blockIdx.x*256 + threadIdx.x)*4;
  const int row = (int)(i >> 9);
  float4 a = *(float4*)(out+i);
  float Z = Zp[row];
  if (ks > 1){
    Z += Zp[NN+row] + Zp[2*NN+row] + Zp[3*NN+row];
    const float4 b1 = *(const float4*)(P1+i);
    const float4 b2 = *(const float4*)(P2+i);
    const float4 b3 = *(const float4*)(P3+i);
    a.x += b1.x+b2.x+b3.x; a.y += b1.y+b2.y+b3.y;
    a.z += b1.z+b2.z+b3.z; a.w += b1.w+b2.w+b3.w;
  }
  const float s = 1.f/Z;
  a.x*=s; a.y*=s; a.z*=s; a.w*=s;
  a.x = (a.x>0.f)?a.x:expm1f(a.x);
  a.y = (a.y>0.f)?a.y:expm1f(a.y);
  a.z = (a.z>0.f)?a.z:expm1f(a.z);
  a.w = (a.w>0.f)?a.w:expm1f(a.w);
  *(float4*)(out+i) = a;
}

extern "C" void kernel_launch(void* const* d_in, const int* in_sizes, int n_in,
                              void* d_out, int out_size, void* d_ws, size_t ws_size,
                              hipStream_t stream) {
  (void)in_sizes; (void)n_in; (void)out_size;
  const int*   adj  = (const int*)d_in[0];
  const float* X    = (const float*)d_in[1];
  const float* W    = (const float*)d_in[2];
  const float* attn = (const float*)d_in[3];
  float* out = (float*)d_out;
  char* ws = (char*)d_ws;
  short*  HT   = (short*)(ws);                 // 8 MB
  short*  Xb   = (short*)(ws + 8388608);       // 8 MB
  short*  WbT  = (short*)(ws + 16777216);      // 0.5 MB
  uint32* uwb  = (uint32*)(ws + 17301504);     // 32 KB
  float2* rowAB= (float2*)(ws + 17334272);     // 64 KB
  float*  wa   = (float*)(ws + 17399808);      // 4 KB
  float*  Zp   = (float*)(ws + 17403904);      // 128 KB
  float*  P1   = (float*)(ws + 17534976);      // 16.78 MB
  float*  P2   = (float*)(ws + 34312192);      // 16.78 MB
  float*  P3   = (float*)(ws + 51089408);      // 16.78 MB (end ~68 MB)
  const int KS = (ws_size >= 67866624ull) ? 4 : 1;
  const int ksteps = 128/KS;                   // BK=64 steps per slice

  k_wa   <<<dim3(256),    dim3(256), 0, stream>>>(W, attn, wa);
  k_tw   <<<dim3(8,8),    dim3(256), 0, stream>>>(W, WbT);
  k_prep <<<dim3(2048),   dim3(256), 0, stream>>>(X, wa, Xb, rowAB, uwb);
  k_gemm1<<<dim3(64,4),   dim3(256), 0, stream>>>(Xb, WbT, HT);
  k_pv   <<<dim3(128*KS), dim3(256), 0, stream>>>(adj, HT, uwb, rowAB, Zp, out, P1, P2, P3, ksteps, KS);
  k_red  <<<dim3(4096),   dim3(256), 0, stream>>>(P1, P2, P3, Zp, out, KS);
}

// Round 24
// 147.588 us; speedup vs baseline: 1.0363x; 1.0363x over previous
//
#include <hip/hip_runtime.h>
#include <hip/hip_bf16.h>
#include <cstdint>

#define NN 8192
#define F 512
#define LOG2E 1.4426950408889634f

typedef __attribute__((ext_vector_type(8))) short bf16x8;
typedef __attribute__((ext_vector_type(4))) float f32x4;
typedef unsigned int uint32;
typedef unsigned long long u64;
typedef unsigned char uchar;

__device__ __forceinline__ short f2bf(float x){
  __hip_bfloat16 h = __float2bfloat16(x);
  return *reinterpret_cast<short*>(&h);
}

// ---------- wa = W @ a1 / W @ a2 ----------
__global__ __launch_bounds__(256) void k_wa(const float* __restrict__ W, const float* __restrict__ attn,
                     float* __restrict__ wa){
  const int lane = threadIdx.x&63, wid = threadIdx.x>>6;
  const int id = blockIdx.x*4 + wid;
  const int b = id>>9, c = id&511;
  const float4* Wr = (const float4*)(W + (size_t)c*F);
  const float4* av = (const float4*)(attn + b*F);
  float s = 0.f;
  #pragma unroll
  for (int h=0;h<2;++h){
    const int k = lane + h*64;
    const float4 wv = Wr[k], a = av[k];
    s += wv.x*a.x + wv.y*a.y + wv.z*a.z + wv.w*a.w;
  }
  for (int off=32;off;off>>=1) s += __shfl_down(s,off);
  if (lane==0) wa[id] = s;
}

// ---------- W^T -> bf16 via LDS tile ----------
__global__ __launch_bounds__(256) void k_tw(const float* __restrict__ W, short* __restrict__ WbT){
  __shared__ short t[64][72];
  const int k0 = blockIdx.x*64, n0 = blockIdx.y*64;
  #pragma unroll
  for (int it=0;it<16;++it){
    const int idx = it*256 + threadIdx.x;
    const int r = idx>>6, c = idx&63;
    t[r][c] = f2bf(W[(size_t)(k0+r)*F + n0 + c]);
  }
  __syncthreads();
  #pragma unroll
  for (int it=0;it<2;++it){
    const int idx = it*256 + threadIdx.x;
    const int n = idx>>3, g = idx&7;
    short v[8];
    #pragma unroll
    for (int e=0;e<8;++e) v[e] = t[g*8+e][n];
    *(uint4*)(WbT + (size_t)(n0+n)*F + k0 + g*8) = *(const uint4*)v;
  }
}

// ---------- fused: X->bf16 + rowAB + packed bf16 (u,w) ----------
__global__ __launch_bounds__(256) void k_prep(const float* __restrict__ X, const float* __restrict__ wa,
    short* __restrict__ Xb, float2* __restrict__ rowAB, uint32* __restrict__ uwb){
  const int lane = threadIdx.x&63, wid = threadIdx.x>>6;
  const int row = blockIdx.x*4 + wid;
  const float4* X4 = (const float4*)(X + (size_t)row*F);
  const float4* A4 = (const float4*)wa;
  const float4* B4 = (const float4*)(wa + F);
  uint2* Xb4 = (uint2*)(Xb + (size_t)row*F);
  float a1 = 0.f, a2 = 0.f;
  #pragma unroll
  for (int h=0;h<2;++h){
    const int c = lane + h*64;
    const float4 x = X4[c];
    const float4 a = A4[c];
    const float4 b = B4[c];
    a1 += x.x*a.x + x.y*a.y + x.z*a.z + x.w*a.w;
    a2 += x.x*b.x + x.y*b.y + x.z*b.z + x.w*b.w;
    short o[4] = {f2bf(x.x),f2bf(x.y),f2bf(x.z),f2bf(x.w)};
    Xb4[c] = *(const uint2*)o;
  }
  for (int off=32;off;off>>=1){ a1 += __shfl_down(a1,off); a2 += __shfl_down(a2,off); }
  if (lane==0){
    const float s1 = a1*LOG2E, s2 = a2*LOG2E;
    rowAB[row] = make_float2(exp2f(s1), exp2f(0.2f*s1));
    const float u = exp2f(s2), w = exp2f(0.2f*s2);
    uwb[row] = (uint32)(unsigned short)f2bf(u) | ((uint32)(unsigned short)f2bf(w)<<16);
  }
}

// ---------- GEMM1: h = Xb @ WbT^T, writes HT[feature][node] bf16 ----------
__global__ __launch_bounds__(256,2) void k_gemm1(const short* __restrict__ Xb,
    const short* __restrict__ WbT, short* __restrict__ HT){
  __shared__ char smem[33280];
  short* At = (short*)smem;
  short* Bt = (short*)(smem + 16384);
  const int tid=threadIdx.x, lane=tid&63, wid=tid>>6;
  const int m0 = blockIdx.x*128, n0 = blockIdx.y*128;
  f32x4 acc[2][8];
  #pragma unroll
  for (int a=0;a<2;++a)
    #pragma unroll
    for (int b=0;b<8;++b) acc[a][b] = (f32x4){0.f,0.f,0.f,0.f};

  for (int t=0;t<8;++t){
    const int k0 = t*64;
    __syncthreads();
    #pragma unroll
    for (int rnd=0;rnd<4;++rnd){
      const int s = rnd*256 + tid;
      const int n = s>>3, kc = s&7;
      uint4 va = *(const uint4*)(Xb  + (size_t)(m0+n)*F + k0 + kc*8);
      uint4 vb = *(const uint4*)(WbT + (size_t)(n0+n)*F + k0 + kc*8);
      const int off = n*128 + ((kc^(n&7))*16);
      *(uint4*)((char*)At + off) = va;
      *(uint4*)((char*)Bt + off) = vb;
    }
    __syncthreads();
    #pragma unroll
    for (int ks=0;ks<2;++ks){
      const int kc = ks*4 + (lane>>4);
      int r0 = wid*32 + (lane&15);
      int r1 = r0 + 16;
      bf16x8 af0 = *(const bf16x8*)((char*)At + r0*128 + ((kc^(r0&7))*16));
      bf16x8 af1 = *(const bf16x8*)((char*)At + r1*128 + ((kc^(r1&7))*16));
      #pragma unroll
      for (int nf=0;nf<8;++nf){
        const int c = nf*16 + (lane&15);
        bf16x8 bf = *(const bf16x8*)((char*)Bt + c*128 + ((kc^(c&7))*16));
        acc[0][nf] = __builtin_amdgcn_mfma_f32_16x16x32_bf16(af0, bf, acc[0][nf],0,0,0);
        acc[1][nf] = __builtin_amdgcn_mfma_f32_16x16x32_bf16(af1, bf, acc[1][nf],0,0,0);
      }
    }
  }
  __syncthreads();
  short* ct = (short*)smem;                 // [128][130] bf16
  #pragma unroll
  for (int mf=0;mf<2;++mf)
    #pragma unroll
    for (int nf=0;nf<8;++nf)
      #pragma unroll
      for (int q=0;q<4;++q){
        int r = wid*32 + mf*16 + (lane>>4)*4 + q;
        int c = nf*16 + (lane&15);
        ct[r*130+c] = f2bf(acc[mf][nf][q]);
      }
  __syncthreads();
  {
    const int c = tid>>1, ih0 = (tid&1)*64;
    #pragma unroll
    for (int i8=0;i8<8;++i8){
      short v[8];
      #pragma unroll
      for (int e=0;e<8;++e) v[e] = ct[(ih0+i8*8+e)*130 + c];
      *(uint4*)(HT + (size_t)(n0+c)*NN + m0 + ih0 + i8*8) = *(const uint4*)v;
    }
  }
}

// ---------- PV fused v14 (R20, best): dual B-reg sets, BK=64, 2 barriers/step ----------
// BM=64, BN=512, BK=64, 4 waves of 64x128, split-K=4. LDS 80KB -> 2 blocks/CU.
__global__ __launch_bounds__(256,2) void k_pv(const int* __restrict__ adj,
    const short* __restrict__ HT, const uint32* __restrict__ uwb,
    const float2* __restrict__ rowAB, float* __restrict__ Zp,
    float* __restrict__ P0, float* __restrict__ P1,
    float* __restrict__ P2, float* __restrict__ P3, int ksteps, int KS){
  __shared__ short Bt[512*64];       // 64 KB : row=feature, 128B/row, chunk^=(f&7)
  __shared__ short At[64*64];        // 8 KB  : row=out-row, same swizzle
  __shared__ uint32 uwl[2048];       // 8 KB packed bf16 (u,w) for this k-slice
  const int tid=threadIdx.x, lane=tid&63, wid=tid>>6;
  // XCD-affine mapping (R16-verified): XCD pair {2k,2k+1} owns kz=k.
  int mx, kz;
  if (KS == 4){
    const int id = blockIdx.x;
    kz = (id&7)>>1;
    mx = ((id>>3)<<1) + (id&1);
  } else { kz = 0; mx = blockIdx.x; }
  const int m0 = mx*64;
  const int kz0 = kz*(ksteps*64);
  float* const outs[4] = {P0,P1,P2,P3};
  float* outP = outs[kz];

  // ---- stage uw slice (2048 u32) ----
  {
    const uint4* src = (const uint4*)(uwb + kz0);
    uint4 v0 = src[tid], v1 = src[256+tid];
    ((uint4*)uwl)[tid] = v0; ((uint4*)uwl)[256+tid] = v1;
  }

  // ---- B staging: reg j covers row f = h*256 + j*32 + (tid>>3), chunk c = tid&7,
  //      holding source kc = c ^ (f&7) = (tid&7)^((tid>>3)&7) (h,j-independent).
  const int kcs = (tid&7) ^ ((tid>>3)&7);
  const short* gBa = HT + (size_t)(tid>>3)*NN + kz0 + kcs*8;  // + (h*256+j*32)*NN + t*64

  // ---- AGEN geometry: row ar=tid>>2, col-group aq=tid&3 (8 k per half)
  const int ar = tid>>2, aq = tid&3;
  const float2 E = rowAB[m0 + ar];
  const float A0 = E.x, B0c = E.y;
  const int* adjp = adj + (size_t)(m0+ar)*NN + kz0 + aq*8;    // + t*64 + h*32
  const int aoff0 = ar*128 + (((aq  ) ^ (ar&7))*16);          // h=0: chunk aq
  const int aoff1 = ar*128 + (((aq+4) ^ (ar&7))*16);          // h=1: chunk aq+4

  f32x4 acc[4][8];
  #pragma unroll
  for (int i=0;i<4;++i)
    #pragma unroll
    for (int j=0;j<8;++j) acc[i][j] = (f32x4){0.f,0.f,0.f,0.f};
  float zacc = 0.f;

  uint4 b0,b1,b2,b3,b4,b5,b6,b7;   // B regs: half 0
  uint4 c0,c1,c2,c3,c4,c5,c6,c7;   // B regs: half 1
  int4  aA0,aA1, aB0,aB1;          // adjacency sets: A=half0, B=half1 of step

#define PV_BLOAD_H0(tt) { \
    const short* g = gBa + (size_t)(tt)*64; \
    b0 = *(const uint4*)(g);                   b1 = *(const uint4*)(g + (size_t)1*32*NN); \
    b2 = *(const uint4*)(g + (size_t)2*32*NN); b3 = *(const uint4*)(g + (size_t)3*32*NN); \
    b4 = *(const uint4*)(g + (size_t)4*32*NN); b5 = *(const uint4*)(g + (size_t)5*32*NN); \
    b6 = *(const uint4*)(g + (size_t)6*32*NN); b7 = *(const uint4*)(g + (size_t)7*32*NN); }

#define PV_BLOAD_H1(tt) { \
    const short* g = gBa + (size_t)256*NN + (size_t)(tt)*64; \
    c0 = *(const uint4*)(g);                   c1 = *(const uint4*)(g + (size_t)1*32*NN); \
    c2 = *(const uint4*)(g + (size_t)2*32*NN); c3 = *(const uint4*)(g + (size_t)3*32*NN); \
    c4 = *(const uint4*)(g + (size_t)4*32*NN); c5 = *(const uint4*)(g + (size_t)5*32*NN); \
    c6 = *(const uint4*)(g + (size_t)6*32*NN); c7 = *(const uint4*)(g + (size_t)7*32*NN); }

#define PV_BWRITE_H0() { \
    uint4* d = (uint4*)Bt; \
    d[      tid] = b0; d[ 256+tid] = b1; d[ 512+tid] = b2; d[ 768+tid] = b3; \
    d[1024+tid] = b4; d[1280+tid] = b5; d[1536+tid] = b6; d[1792+tid] = b7; }

#define PV_BWRITE_H1() { \
    uint4* d = (uint4*)Bt + 2048; \
    d[      tid] = c0; d[ 256+tid] = c1; d[ 512+tid] = c2; d[ 768+tid] = c3; \
    d[1024+tid] = c4; d[1280+tid] = c5; d[1536+tid] = c6; d[1792+tid] = c7; }

#define PV_ALOAD(r0v,r1v,h,tt) { \
    r0v = *(const int4*)(adjp + (size_t)(tt)*64 + (h)*32); \
    r1v = *(const int4*)(adjp + (size_t)(tt)*64 + (h)*32 + 4); }

#define PV_AGEN(aoffv, r0v, r1v, h, tt) { \
    const uint32* uwt = &uwl[(tt)*64 + (h)*32 + aq*8]; \
    const uint4 u0 = *(const uint4*)uwt; \
    const uint4 u1 = *(const uint4*)(uwt+4); \
    const uint32 pk[8] = {u0.x,u0.y,u0.z,u0.w,u1.x,u1.y,u1.z,u1.w}; \
    const int    aa[8] = {r0v.x,r0v.y,r0v.z,r0v.w,r1v.x,r1v.y,r1v.z,r1v.w}; \
    short av[8]; \
    _Pragma("unroll") \
    for (int e=0;e<8;++e){ \
      const float u = __uint_as_float(pk[e]<<16); \
      const float w = __uint_as_float(pk[e]&0xffff0000u); \
      float v = fmaxf(A0*u, B0c*w); \
      v = (aa[e] > 0) ? v : 0.f; \
      zacc += v; \
      av[e] = f2bf(v); } \
    *(uint4*)((char*)At + (aoffv)) = *(const uint4*)av; }

#define PV_MFMA64() { \
    _Pragma("unroll") \
    for (int ks=0;ks<2;++ks){ \
      const int kc = ks*4 + (lane>>4); \
      bf16x8 af[4]; \
      _Pragma("unroll") \
      for (int mf=0;mf<4;++mf){ \
        const int r = mf*16 + (lane&15); \
        af[mf] = *(const bf16x8*)((char*)At + r*128 + ((kc^(r&7))*16)); } \
      _Pragma("unroll") \
      for (int nf=0;nf<8;++nf){ \
        const int c = wid*128 + nf*16 + (lane&15); \
        const bf16x8 bv = *(const bf16x8*)((char*)Bt + c*128 + ((kc^(c&7))*16)); \
        _Pragma("unroll") \
        for (int mf=0;mf<4;++mf) \
          acc[mf][nf] = __builtin_amdgcn_mfma_f32_16x16x32_bf16(af[mf], bv, acc[mf][nf],0,0,0); } } }

  // ---- prologue: step 0 fully staged (both halves loaded up-front) ----
  PV_ALOAD(aA0,aA1, 0, 0);
  PV_ALOAD(aB0,aB1, 1, 0);
  PV_BLOAD_H0(0);
  PV_BLOAD_H1(0);
  __syncthreads();                 // uwl visible
  PV_BWRITE_H0();
  PV_AGEN(aoff0, aA0,aA1, 0, 0);
  PV_BWRITE_H1();
  PV_AGEN(aoff1, aB0,aB1, 1, 0);
  __syncthreads();                 // tiles(0) visible

  // ---- main loop: one 64-K step per iteration, 2 barriers/step ----
  for (int t=0; t<ksteps; ++t){
    // issue ALL next-step loads before compute (full MFMA phase to land)
    if (t+1 < ksteps){
      PV_BLOAD_H0(t+1);
      PV_BLOAD_H1(t+1);
      PV_ALOAD(aA0,aA1, 0, t+1);
      PV_ALOAD(aB0,aB1, 1, t+1);
    }
    PV_MFMA64();
    __syncthreads();               // reads of Bt/At done
    if (t+1 < ksteps){
      PV_BWRITE_H0();              // all loads had the MFMA phase in flight
      PV_AGEN(aoff0, aA0,aA1, 0, t+1);
      PV_BWRITE_H1();
      PV_AGEN(aoff1, aB0,aB1, 1, t+1);
      __syncthreads();             // tiles(t+1) visible
    }
  }

  // per-slice Z: 4 threads per row
  zacc += __shfl_xor(zacc, 1);
  zacc += __shfl_xor(zacc, 2);
  if (aq == 0) Zp[(size_t)kz*NN + m0 + ar] = zacc;
  // raw f32 partial store
  #pragma unroll
  for (int mf=0;mf<4;++mf)
    #pragma unroll
    for (int nf=0;nf<8;++nf){
      const int col = wid*128 + nf*16 + (lane&15);
      #pragma unroll
      for (int qq=0;qq<4;++qq){
        const int row = m0 + mf*16 + (lane>>4)*4 + qq;
        outP[(size_t)row*F + col] = acc[mf][nf][qq];
      }
    }
#undef PV_BLOAD_H0
#undef PV_BLOAD_H1
#undef PV_BWRITE_H0
#undef PV_BWRITE_H1
#undef PV_ALOAD
#undef PV_AGEN
#undef PV_MFMA64
}

// ---------- reduce: out = elu( (P0+P1+P2+P3) / Z ) ----------
__global__ __launch_bounds__(256) void k_red(const float* __restrict__ P1,
    const float* __restrict__ P2, const float* __restrict__ P3,
    const float* __restrict__ Zp, float* __restrict__ out, int ks){
  const size_t i = ((size_t)blockIdx.x*256 + threadIdx.x)*4;
  const int row = (int)(i >> 9);
  float4 a = *(float4*)(out+i);
  float Z = Zp[row];
  if (ks > 1){
    Z += Zp[NN+row] + Zp[2*NN+row] + Zp[3*NN+row];
    const float4 b1 = *(const float4*)(P1+i);
    const float4 b2 = *(const float4*)(P2+i);
    const float4 b3 = *(const float4*)(P3+i);
    a.x += b1.x+b2.x+b3.x; a.y += b1.y+b2.y+b3.y;
    a.z += b1.z+b2.z+b3.z; a.w += b1.w+b2.w+b3.w;
  }
  const float s = 1.f/Z;
  a.x*=s; a.y*=s; a.z*=s; a.w*=s;
  a.x = (a.x>0.f)?a.x:expm1f(a.x);
  a.y = (a.y>0.f)?a.y:expm1f(a.y);
  a.z = (a.z>0.f)?a.z:expm1f(a.z);
  a.w = (a.w>0.f)?a.w:expm1f(a.w);
  *(float4*)(out+i) = a;
}

extern "C" void kernel_launch(void* const* d_in, const int* in_sizes, int n_in,
                              void* d_out, int out_size, void* d_ws, size_t ws_size,
                              hipStream_t stream) {
  (void)in_sizes; (void)n_in; (void)out_size;
  const int*   adj  = (const int*)d_in[0];
  const float* X    = (const float*)d_in[1];
  const float* W    = (const float*)d_in[2];
  const float* attn = (const float*)d_in[3];
  float* out = (float*)d_out;
  char* ws = (char*)d_ws;
  short*  HT   = (short*)(ws);                 // 8 MB
  short*  Xb   = (short*)(ws + 8388608);       // 8 MB
  short*  WbT  = (short*)(ws + 16777216);      // 0.5 MB
  uint32* uwb  = (uint32*)(ws + 17301504);     // 32 KB
  float2* rowAB= (float2*)(ws + 17334272);     // 64 KB
  float*  wa   = (float*)(ws + 17399808);      // 4 KB
  float*  Zp   = (float*)(ws + 17403904);      // 128 KB
  float*  P1   = (float*)(ws + 17534976);      // 16.78 MB
  float*  P2   = (float*)(ws + 34312192);      // 16.78 MB
  float*  P3   = (float*)(ws + 51089408);      // 16.78 MB (end ~68 MB)
  const int KS = (ws_size >= 67866624ull) ? 4 : 1;
  const int ksteps = 128/KS;                   // BK=64 steps per slice

  k_wa   <<<dim3(256),    dim3(256), 0, stream>>>(W, attn, wa);
  k_tw   <<<dim3(8,8),    dim3(256), 0, stream>>>(W, WbT);
  k_prep <<<dim3(2048),   dim3(256), 0, stream>>>(X, wa, Xb, rowAB, uwb);
  k_gemm1<<<dim3(64,4),   dim3(256), 0, stream>>>(Xb, WbT, HT);
  k_pv   <<<dim3(128*KS), dim3(256), 0, stream>>>(adj, HT, uwb, rowAB, Zp, out, P1, P2, P3, ksteps, KS);
  k_red  <<<dim3(4096),   dim3(256), 0, stream>>>(P1, P2, P3, Zp, out, KS);
}